// Round 3
// baseline (250.304 us; speedup 1.0000x reference)
//
#include <hip/hip_runtime.h>
#include <cstdint>

typedef unsigned short u16;
typedef __attribute__((ext_vector_type(8))) short short8;
typedef __attribute__((ext_vector_type(4))) float f32x4;

#define NTOK 2048
#define CDIM 1024
#define C3   3072
#define NH   8
#define HD   128

__device__ __forceinline__ float bf2f(u16 u) {
    return __uint_as_float(((unsigned)u) << 16);
}
__device__ __forceinline__ u16 f2bf(float f) {
    unsigned u = __float_as_uint(f);
    u += 0x7fffu + ((u >> 16) & 1u);
    return (u16)(u >> 16);
}

// ---------------------------------------------------------------- K1: f32->bf16
__global__ __launch_bounds__(256) void k_cast(const float* __restrict__ x,
                                              const float* __restrict__ w,
                                              u16* __restrict__ xb,
                                              u16* __restrict__ wb) {
    int t = blockIdx.x * blockDim.x + threadIdx.x;
    int stride = gridDim.x * blockDim.x;
    for (int i = t; i < (NTOK * CDIM) / 4; i += stride) {
        float4 v = ((const float4*)x)[i];
        ushort4 o;
        o.x = f2bf(v.x); o.y = f2bf(v.y); o.z = f2bf(v.z); o.w = f2bf(v.w);
        ((ushort4*)xb)[i] = o;
    }
    for (int i = t; i < (C3 * CDIM) / 4; i += stride) {
        float4 v = ((const float4*)w)[i];
        ushort4 o;
        o.x = f2bf(v.x); o.y = f2bf(v.y); o.z = f2bf(v.z); o.w = f2bf(v.w);
        ((ushort4*)wb)[i] = o;
    }
}

// ---------------------------------------------------------------- K2: generic bf16 GEMM, C = A[M,K] @ B[N,K]^T
// EPI 0: write bf16. EPI 1: write u8 (acc*scale > 0.75).
template <int EPI>
__global__ __launch_bounds__(256) void k_gemm_bt(const u16* __restrict__ A,
                                                 const u16* __restrict__ B,
                                                 void* __restrict__ Cv, int K,
                                                 int lda, int ldb, int ldc,
                                                 float scale) {
    __shared__ u16 As[128][40];
    __shared__ u16 Bs[128][40];
    const int tid = threadIdx.x;
    const int lane = tid & 63;
    const int wid = tid >> 6;
    const int wm = wid >> 1, wn = wid & 1;
    const int q = lane >> 4, l16 = lane & 15;
    const int m0 = blockIdx.y * 128, n0 = blockIdx.x * 128;

    f32x4 zero4 = {0.f, 0.f, 0.f, 0.f};
    f32x4 acc[4][4];
#pragma unroll
    for (int i = 0; i < 4; i++)
#pragma unroll
        for (int j = 0; j < 4; j++) acc[i][j] = zero4;

    for (int k0 = 0; k0 < K; k0 += 32) {
        __syncthreads();
        {
            int v = tid;
            int row = v >> 2, kc = (v & 3) * 8;
            *(short8*)&As[row][kc] =
                *(const short8*)&A[(long long)(m0 + row) * lda + k0 + kc];
            *(short8*)&Bs[row][kc] =
                *(const short8*)&B[(long long)(n0 + row) * ldb + k0 + kc];
            v = tid + 256;
            row = v >> 2; kc = (v & 3) * 8;
            *(short8*)&As[row][kc] =
                *(const short8*)&A[(long long)(m0 + row) * lda + k0 + kc];
            *(short8*)&Bs[row][kc] =
                *(const short8*)&B[(long long)(n0 + row) * ldb + k0 + kc];
        }
        __syncthreads();
        short8 af[4], bfr[4];
#pragma unroll
        for (int tm = 0; tm < 4; tm++)
            af[tm] = *(const short8*)&As[wm * 64 + tm * 16 + l16][q * 8];
#pragma unroll
        for (int tn = 0; tn < 4; tn++)
            bfr[tn] = *(const short8*)&Bs[wn * 64 + tn * 16 + l16][q * 8];
#pragma unroll
        for (int tm = 0; tm < 4; tm++)
#pragma unroll
            for (int tn = 0; tn < 4; tn++)
                acc[tm][tn] = __builtin_amdgcn_mfma_f32_16x16x32_bf16(
                    af[tm], bfr[tn], acc[tm][tn], 0, 0, 0);
    }

#pragma unroll
    for (int tm = 0; tm < 4; tm++) {
#pragma unroll
        for (int tn = 0; tn < 4; tn++) {
#pragma unroll
            for (int r = 0; r < 4; r++) {
                int row = m0 + wm * 64 + tm * 16 + q * 4 + r;
                int col = n0 + wn * 64 + tn * 16 + l16;
                float v = acc[tm][tn][r];
                long long off = (long long)row * ldc + col;
                if (EPI == 0) {
                    ((u16*)Cv)[off] = f2bf(v);
                } else {
                    ((unsigned char*)Cv)[off] = (v * scale > 0.75f) ? 1 : 0;
                }
            }
        }
    }
}

// ---------------------------------------------------------------- K3: per-row L2 normalize q/k/v heads + x_ori
__global__ __launch_bounds__(256) void k_norm(const u16* __restrict__ qkv,
                                              u16* __restrict__ Qn,
                                              u16* __restrict__ Kn,
                                              u16* __restrict__ Vn,
                                              float* __restrict__ out) {
    int n = blockIdx.x;
    int lane = threadIdx.x & 63;
    int w = threadIdx.x >> 6;
    for (int s = w; s < 24; s += 4) {
        int which = s >> 3;  // 0=q 1=k 2=v
        int h = s & 7;
        int d0 = lane * 2;
        const u16* src = qkv + (long long)n * C3 + which * CDIM + h * HD + d0;
        u16 u0 = src[0], u1 = src[1];
        float f0 = bf2f(u0), f1 = bf2f(u1);
        float ss = f0 * f0 + f1 * f1;
#pragma unroll
        for (int off = 1; off < 64; off <<= 1) ss += __shfl_xor(ss, off);
        float rn = rsqrtf(ss);
        u16* dst = (which == 0 ? Qn : which == 1 ? Kn : Vn) +
                   (long long)n * CDIM + h * HD + d0;
        ushort2 nv;
        nv.x = f2bf(f0 * rn);
        nv.y = f2bf(f1 * rn);
        *(ushort2*)dst = nv;
        if (which == 2) {
            float2 fo;
            fo.x = f0; fo.y = f1;
            *(float2*)&out[(long long)n * 2048 + 1024 + h * HD + d0] = fo;
        }
    }
}

// ---------------------------------------------------------------- K3b: tiled transpose Vt[c][n] = v[n][c] (raw v)
__global__ __launch_bounds__(256) void k_vt(const u16* __restrict__ qkv,
                                            u16* __restrict__ Vt) {
    __shared__ u16 T[64][72];
    const int n0 = blockIdx.x * 64;
    const int c0 = blockIdx.y * 64;
    const int tid = threadIdx.x;
    {
        int nl = tid >> 2, cc = (tid & 3) * 16;
        const u16* src = &qkv[(long long)(n0 + nl) * C3 + 2 * CDIM + c0 + cc];
        *(short8*)&T[nl][cc] = *(const short8*)&src[0];
        *(short8*)&T[nl][cc + 8] = *(const short8*)&src[8];
    }
    __syncthreads();
    {
        int cl = tid >> 2, nc = (tid & 3) * 16;
        ushort va[16];
#pragma unroll
        for (int i = 0; i < 16; i++) va[i] = T[nc + i][cl];
        u16* dst = &Vt[(long long)(c0 + cl) * NTOK + n0 + nc];
        *(short8*)&dst[0] = *(short8*)&va[0];
        *(short8*)&dst[8] = *(short8*)&va[8];
    }
}

// ---------------------------------------------------------------- K3c: zero Xacc
__global__ __launch_bounds__(256) void k_zero(float* __restrict__ p) {
    int idx = blockIdx.x * 256 + threadIdx.x;
    f32x4 z = {0.f, 0.f, 0.f, 0.f};
    ((f32x4*)p)[idx] = z;
}

// ---------------------------------------------------------------- K4: fused QK->exp->P + PV (flash-style, unnormalized)
// grid (32 i-tiles, 4 j-chunks, 8 heads) = 1024 blocks, 4 blocks/CU (LDS=40960B)
__global__ __launch_bounds__(256, 4) void k_attn3(const u16* __restrict__ Qn,
                                                  const u16* __restrict__ Kn,
                                                  const u16* __restrict__ Vt,
                                                  const float* __restrict__ cls,
                                                  u16* __restrict__ P,
                                                  float* __restrict__ Spart,
                                                  float* __restrict__ Xacc) {
    __shared__ u16 Kf[8192];  // QK B-frags, slot ((tn*4+kt)*64+lane)*8
    __shared__ u16 Vf[8192];  // PV B-frags, slot ((n*2+ks)*64+lane)*8
    __shared__ u16 Et[4096];  // e tile 64x64 bf16, XOR-chunk swizzled
    const int h = blockIdx.z;
    const int jc = blockIdx.y;
    const int i0 = blockIdx.x * 64;
    const int jbase = jc * 512;
    const int tid = threadIdx.x, lane = tid & 63, wid = tid >> 6;
    const int q = lane >> 4, l16 = lane & 15;
    const int wm = wid >> 1, wn = wid & 1;

    // resident Q fragments (i range: wm*32 .. +31)
    short8 af[2][4];
#pragma unroll
    for (int m = 0; m < 2; m++)
#pragma unroll
        for (int kt = 0; kt < 4; kt++)
            af[m][kt] = *(const short8*)&Qn[(long long)(i0 + wm * 32 + m * 16 + l16) * CDIM +
                                            h * HD + kt * 32 + q * 8];
    float cls_i[2][4];
#pragma unroll
    for (int m = 0; m < 2; m++)
#pragma unroll
        for (int r = 0; r < 4; r++)
            cls_i[m][r] = cls[i0 + wm * 32 + m * 16 + q * 4 + r] - 0.1f;

    f32x4 zero4 = {0.f, 0.f, 0.f, 0.f};
    f32x4 pv[2][4];
#pragma unroll
    for (int m = 0; m < 2; m++)
#pragma unroll
        for (int n = 0; n < 4; n++) pv[m][n] = zero4;
    float sums[2][4] = {{0.f, 0.f, 0.f, 0.f}, {0.f, 0.f, 0.f, 0.f}};

    for (int jt = 0; jt < 8; ++jt) {
        const int j0 = jbase + jt * 64;
        __syncthreads();  // previous-iter consumers done with Kf/Vf/Et
        {   // stage K tile (64 j-rows x 128 c) fragment-ready
            int r = tid >> 2;
            int tn = r >> 4, s16 = r & 15;
            const u16* src = &Kn[(long long)(j0 + r) * CDIM + h * HD + (tid & 3) * 32];
#pragma unroll
            for (int i = 0; i < 4; i++) {
                int chunk = (tid & 3) * 4 + i;
                int kt = chunk >> 2, qq = chunk & 3;
                *(short8*)&Kf[((tn * 4 + kt) * 64 + qq * 16 + s16) * 8] =
                    *(const short8*)&src[i * 8];
            }
        }
        {   // stage V tile (128 d x 64 j) fragment-ready from Vt
            int d = tid >> 1;
            int jh = (tid & 1) * 32;
            const u16* src = &Vt[(long long)(h * HD + d) * NTOK + j0 + jh];
            int n = d >> 4, dl = d & 15;
#pragma unroll
            for (int c = 0; c < 4; c++) {
                int jc8 = (jh >> 3) + c;
                int ks = jc8 >> 2, qq = jc8 & 3;
                *(short8*)&Vf[((n * 2 + ks) * 64 + qq * 16 + dl) * 8] =
                    *(const short8*)&src[c * 8];
            }
        }
        __syncthreads();
        // QK -> e -> Et (+ row sums)
#pragma unroll
        for (int tn = 0; tn < 2; tn++) {
            int tng = wn * 2 + tn;
            short8 bfr[4];
#pragma unroll
            for (int kt = 0; kt < 4; kt++)
                bfr[kt] = *(const short8*)&Kf[((tng * 4 + kt) * 64 + lane) * 8];
            int j = j0 + tng * 16 + l16;
            float cj = cls[j];
            float sc = 25.f * cj;
#pragma unroll
            for (int m = 0; m < 2; m++) {
                f32x4 acc = zero4;
#pragma unroll
                for (int kt = 0; kt < 4; kt++)
                    acc = __builtin_amdgcn_mfma_f32_16x16x32_bf16(af[m][kt], bfr[kt],
                                                                  acc, 0, 0, 0);
                int ibase = wm * 32 + m * 16 + q * 4;
#pragma unroll
                for (int r = 0; r < 4; r++) {
                    float mk = (cj > cls_i[m][r]) ? 1.f : 0.f;
                    float e = __expf(acc[r] * sc * mk);
                    sums[m][r] += e;
                    int il = ibase + r;
                    int jl = tng * 16 + l16;
                    Et[il * 64 + ((((jl >> 3) ^ (il & 7)) << 3) | (jl & 7))] = f2bf(e);
                }
            }
        }
        __syncthreads();
        {   // coalesced P store from Et
            int il = tid >> 2, c = tid & 3;
            int x = il & 7;
            short8 e0 = *(const short8*)&Et[il * 64 + (((2 * c) ^ x) << 3)];
            short8 e1 = *(const short8*)&Et[il * 64 + (((2 * c + 1) ^ x) << 3)];
            u16* dst = &P[((long long)(h * NTOK + i0 + il)) * NTOK + j0 + c * 16];
            *(short8*)&dst[0] = e0;
            *(short8*)&dst[8] = e1;
        }
        // PV: A from Et (swizzled), B from Vf; out tile i(64) x d(128), wave grid 2x2
#pragma unroll
        for (int ks = 0; ks < 2; ks++) {
            short8 a2[2];
#pragma unroll
            for (int m2 = 0; m2 < 2; m2++) {
                int il = wm * 32 + m2 * 16 + l16;
                int ch = ks * 4 + q;
                a2[m2] = *(const short8*)&Et[il * 64 + ((ch ^ (il & 7)) << 3)];
            }
#pragma unroll
            for (int n2 = 0; n2 < 4; n2++) {
                short8 b2 = *(const short8*)&Vf[(((wn * 4 + n2) * 2 + ks) * 64 + lane) * 8];
#pragma unroll
                for (int m2 = 0; m2 < 2; m2++)
                    pv[m2][n2] = __builtin_amdgcn_mfma_f32_16x16x32_bf16(
                        a2[m2], b2, pv[m2][n2], 0, 0, 0);
            }
        }
    }
    // row-sum partials (race-free: one writer per (wn,jc,h,row))
#pragma unroll
    for (int m = 0; m < 2; m++)
#pragma unroll
        for (int r = 0; r < 4; r++) {
            float s = sums[m][r];
            s += __shfl_xor(s, 1);
            s += __shfl_xor(s, 2);
            s += __shfl_xor(s, 4);
            s += __shfl_xor(s, 8);
            if (l16 == 0)
                Spart[((wn * 4 + jc) * NH + h) * NTOK + i0 + wm * 32 + m * 16 + q * 4 + r] = s;
        }
    // accumulate unnormalized PV into Xacc
#pragma unroll
    for (int m2 = 0; m2 < 2; m2++)
#pragma unroll
        for (int n2 = 0; n2 < 4; n2++)
#pragma unroll
            for (int r = 0; r < 4; r++) {
                int i = i0 + wm * 32 + m2 * 16 + q * 4 + r;
                int d = wn * 64 + n2 * 16 + l16;
                atomicAdd(&Xacc[(long long)i * CDIM + h * HD + d], pv[m2][n2][r]);
            }
}

// ---------------------------------------------------------------- K4b: Srow = sum of 8 partials
__global__ __launch_bounds__(256) void k_srow(const float* __restrict__ Spart,
                                              float* __restrict__ Srow) {
    int t = blockIdx.x * 256 + threadIdx.x;  // t = h*2048 + i, 16384 total
    float s = 0.f;
#pragma unroll
    for (int g = 0; g < 8; g++) s += Spart[g * 16384 + t];
    Srow[t] = s;
}

// ---------------------------------------------------------------- K4c: x = Xacc / Srow -> out cols [0,1024)
__global__ __launch_bounds__(256) void k_comb(const float* __restrict__ Xacc,
                                              const float* __restrict__ Srow,
                                              float* __restrict__ out) {
    int idx = blockIdx.x * 256 + threadIdx.x;
    int base = idx * 4;
    int i = base >> 10, c = base & 1023;
    int h = c >> 7;
    f32x4 v = ((const f32x4*)Xacc)[idx];
    float s = Srow[h * NTOK + i];
    f32x4 o;
    o[0] = v[0] / s; o[1] = v[1] / s; o[2] = v[2] / s; o[3] = v[3] / s;
    *(f32x4*)&out[(long long)i * 2048 + c] = o;
}

// ---------------------------------------------------------------- K6: output2 = renormed masked softmax of head-mean attn
__global__ __launch_bounds__(256) void k_out2(const u16* __restrict__ P,
                                              const float* __restrict__ Srow,
                                              const unsigned char* __restrict__ mask,
                                              float* __restrict__ out2) {
    __shared__ float red[256];
    const int i = blockIdx.x;
    const int t = threadIdx.x;
    float invS[NH];
#pragma unroll
    for (int h = 0; h < NH; h++) invS[h] = 1.f / (8.f * Srow[h * NTOK + i]);
    const int c0 = t * 8;
    float a[8] = {0.f, 0.f, 0.f, 0.f, 0.f, 0.f, 0.f, 0.f};
#pragma unroll
    for (int h = 0; h < NH; h++) {
        short8 p = *(const short8*)&P[((long long)h * NTOK + i) * NTOK + c0];
#pragma unroll
        for (int k = 0; k < 8; k++) a[k] += bf2f((u16)p[k]) * invS[h];
    }
    const unsigned char* mrow = mask + (long long)i * NTOK + c0;
    float e[8];
    unsigned char mk[8];
    float part = 0.f;
#pragma unroll
    for (int k = 0; k < 8; k++) {
        e[k] = __expf(a[k]);
        mk[k] = mrow[k];
        if (mk[k]) part += e[k];
    }
    red[t] = part;
    __syncthreads();
    for (int s = 128; s > 0; s >>= 1) {
        if (t < s) red[t] += red[t + s];
        __syncthreads();
    }
    float invT = 1.f / red[0];
    float o[8];
#pragma unroll
    for (int k = 0; k < 8; k++) o[k] = mk[k] ? e[k] * invT : 0.f;
    float4 o0, o1;
    o0.x = o[0]; o0.y = o[1]; o0.z = o[2]; o0.w = o[3];
    o1.x = o[4]; o1.y = o[5]; o1.z = o[6]; o1.w = o[7];
    float* dst = out2 + (long long)i * NTOK + c0;
    *(float4*)dst = o0;
    *(float4*)(dst + 4) = o1;
}

// ---------------------------------------------------------------- launcher
extern "C" void kernel_launch(void* const* d_in, const int* in_sizes, int n_in,
                              void* d_out, int out_size, void* d_ws,
                              size_t ws_size, hipStream_t stream) {
    (void)in_sizes; (void)n_in; (void)out_size; (void)ws_size;
    const float* x = (const float*)d_in[0];
    const float* cls = (const float*)d_in[1];
    // d_in[2] = fg_score: unused by the reference
    const float* Wq = (const float*)d_in[3];
    float* out = (float*)d_out;
    char* ws = (char*)d_ws;

    u16* Xb = (u16*)(ws + 0);                      //  4 MB  [2048,1024] (dead after QKV gemm)
    u16* Wb = (u16*)(ws + 4194304);                //  6 MB  [3072,1024] (dead after QKV gemm)
    float* Xacc = (float*)(ws + 0);                //  8 MB  [2048,1024] f32, reuses Xb/Wb
    float* Spart = (float*)(ws + 8388608);         // 512 KB [8][8,2048], reuses Wb tail
    u16* QKVb = (u16*)(ws + 10485760);             // 12.6MB [2048,3072]
    u16* Qn = (u16*)(ws + 23068672);               //  4 MB
    u16* Kn = (u16*)(ws + 27262976);               //  4 MB
    u16* Vn = (u16*)(ws + 31457280);               //  4 MB
    u16* Vt = (u16*)(ws + 35651584);               //  4 MB  [1024,2048]
    unsigned char* mask = (unsigned char*)(ws + 39845888);  // 4 MB [2048,2048]
    u16* P = (u16*)(ws + 44040192);                // 67 MB [8,2048,2048]
    float* Srow = (float*)(ws + 111149056);        // 64 KB [8,2048]

    // 1. cast x and W to bf16
    k_cast<<<1024, 256, 0, stream>>>(x, Wq, Xb, Wb);

    // 2. QKV = Xb @ Wb^T  -> bf16 [2048,3072]
    k_gemm_bt<0><<<dim3(C3 / 128, NTOK / 128), 256, 0, stream>>>(
        Xb, Wb, QKVb, CDIM, CDIM, CDIM, C3, 1.f);

    // 3. normalize q/k/v, write x_ori
    k_norm<<<NTOK, 256, 0, stream>>>(QKVb, Qn, Kn, Vn, out);

    // 3b. Vt = v^T (raw v), tiled transpose
    k_vt<<<dim3(NTOK / 64, CDIM / 64), 256, 0, stream>>>(QKVb, Vt);

    // 3c. zero PV accumulator (Xb/Wb now dead)
    k_zero<<<2048, 256, 0, stream>>>(Xacc);

    // 4. sim mask = (Vn @ Vn^T / 8 > 0.75) -> u8
    k_gemm_bt<1><<<dim3(16, 16), 256, 0, stream>>>(
        Vn, Vn, mask, CDIM, CDIM, CDIM, NTOK, 0.125f);

    // 5. fused logits+exp -> P, partial row sums, partial PV -> Xacc
    k_attn3<<<dim3(32, 4, NH), 256, 0, stream>>>(Qn, Kn, Vt, cls, P, Spart, Xacc);

    // 5b. Srow = sum of partials
    k_srow<<<64, 256, 0, stream>>>(Spart, Srow);

    // 5c. x = Xacc / Srow
    k_comb<<<2048, 256, 0, stream>>>(Xacc, Srow, out);

    // 6. output2
    k_out2<<<NTOK, 256, 0, stream>>>(P, Srow, mask, out + (long long)NTOK * 2048);
}